// Round 9
// baseline (16499.063 us; speedup 1.0000x reference)
//
#include <hip/hip_runtime.h>

// ---------------------------------------------------------------------------
// Persistent 2-layer LSTM, MI355X. Round 9: WAVE-AUTONOMOUS steps.
// 8 groups (blockIdx%8), 32 WGs/group: 16 L0-WGs (layer 0) + 16 L1-WGs
// (layer 1). NEW partitioning: each wave owns 8 units x 4 gates (2 MFMA
// n-tiles), so i,f,g,o of a unit live in one lane-quad -> activation by
// 3 shfl_xor, cell state in registers, ZERO __syncthreads in the step loop.
// A-fragments load DIRECTLY global->VGPR (h plane [wg][b][32u] makes every
// frag a contiguous 16 B; batch rows 8-15 are harmless duplicates).
// h-publish: 128-f16 wave-local LDS micro-transpose (lgkmcnt only) then
// 8x16B bypass stores. Flags are per-WAVE (64/layer/group), polled one per
// lane + __all vote. Protocol (relaxed sc0sc1 LLC ops, monotone flags,
// h0 depth-4 / h1 depth-2, out-proj before publish) carried from r8.
// ---------------------------------------------------------------------------

#define T_STEPS 1024
#define WS_FLAG_OFF 0                     // 8 g * 128 ints = 4 KB
#define WS_H0_OFF  4096                   // 8 g * 4 planes * 8 KB
#define WS_H1_OFF  (4096 + 8*4*8192)      // 8 g * 2 planes * 8 KB
#define WS_NEED    (WS_H1_OFF + 8*2*8192) // 397312 B (same as r8, known-good)

typedef _Float16 f16;
typedef _Float16 f16x8 __attribute__((ext_vector_type(8)));
typedef float    f32x4 __attribute__((ext_vector_type(4)));
typedef unsigned long long u64;

__device__ __forceinline__ float sigm_(float x) {
    x = fminf(fmaxf(x, -30.f), 30.f);
    return 1.f / (1.f + __expf(-x));
}
__device__ __forceinline__ float tanh_(float x) {
    x = fminf(fmaxf(x, -15.f), 15.f);
    float e = __expf(-2.f * x);
    return (1.f - e) / (1.f + e);
}

__device__ __forceinline__ u64 ldg64(const u64* p) {
    return __hip_atomic_load(p, __ATOMIC_RELAXED, __HIP_MEMORY_SCOPE_SYSTEM);
}
__device__ __forceinline__ void stg64(u64* p, u64 v) {
    __hip_atomic_store(p, v, __ATOMIC_RELAXED, __HIP_MEMORY_SCOPE_SYSTEM);
}
// 16 B bypass load/store as two u64 system-scope ops (LLC-coherent).
__device__ __forceinline__ f16x8 ld16B(const f16* p) {
    union { u64 u[2]; f16x8 v; } cv;
    cv.u[0] = ldg64((const u64*)p);
    cv.u[1] = ldg64((const u64*)p + 1);
    return cv.v;
}
__device__ __forceinline__ void st16B(f16* p, f16x8 v) {
    union { u64 u[2]; f16x8 x; } cv; cv.x = v;
    stg64((u64*)p, cv.u[0]);
    stg64((u64*)p + 1, cv.u[1]);
}

__device__ __forceinline__ f16x8 pack8(const float* p) {
    float4 a = *(const float4*)p, b = *(const float4*)(p + 4);
    f16x8 f;
    f[0] = (f16)a.x; f[1] = (f16)a.y; f[2] = (f16)a.z; f[3] = (f16)a.w;
    f[4] = (f16)b.x; f[5] = (f16)b.y; f[6] = (f16)b.z; f[7] = (f16)b.w;
    return f;
}

// Poll 64 per-wave flags: lane l loads flag[l]; single __all vote.
__device__ __forceinline__ void wait1(const int* f, int t, int lane) {
    int spins = 0;
    for (;;) {
        int a = __hip_atomic_load(f + lane, __ATOMIC_RELAXED,
                                  __HIP_MEMORY_SCOPE_SYSTEM);
        if (__all(a >= t)) break;
        __builtin_amdgcn_s_sleep(1);
        if (++spins > (1 << 20)) break;   // anti-hang safety valve
    }
}
__device__ __forceinline__ void wait2(const int* fA, int tA,
                                      const int* fB, int tB, int lane) {
    int spins = 0;
    for (;;) {
        int a = __hip_atomic_load(fA + lane, __ATOMIC_RELAXED,
                                  __HIP_MEMORY_SCOPE_SYSTEM);
        int b = __hip_atomic_load(fB + lane, __ATOMIC_RELAXED,
                                  __HIP_MEMORY_SCOPE_SYSTEM);
        if (__all((a >= tA) && (b >= tB))) break;
        __builtin_amdgcn_s_sleep(1);
        if (++spins > (1 << 20)) break;
    }
}

// x A-fragment for step t, batch row b (duplicated for lanes 8-15).
__device__ __forceinline__ f16x8 load_xfrag(const float* __restrict__ x,
                                            int gb8, int t, int b, int q) {
    f16x8 f = {(_Float16)0, (_Float16)0, (_Float16)0, (_Float16)0,
               (_Float16)0, (_Float16)0, (_Float16)0, (_Float16)0};
    const float* xp = x + ((size_t)(gb8 + b) * 1024 + t) * 21;
#pragma unroll
    for (int j = 0; j < 8; ++j) {
        int kl = q * 8 + j;
        if (kl < 21) f[j] = (f16)xp[kl];
    }
    return f;
}

// Activation for one n-tile: each lane activates ITS gate (g0) of its quad's
// unit, then 3 quad shuffles assemble cn/h on the g0==0 lane.
// g0: 0=i(sigm) 1=f(sigm) 2=g(tanh) 3=o(sigm).
__device__ __forceinline__ u64 act_tile(f32x4 acc, float bias, float* c, int g0) {
    union { f16 h[4]; u64 u; } hp;
#pragma unroll
    for (int rr = 0; rr < 4; ++rr) {
        float pre = acc[rr] + bias;
        float A  = (g0 == 2) ? tanh_(pre) : sigm_(pre);
        float s1 = __shfl_xor(A, 1);
        float s2 = __shfl_xor(A, 2);
        float s3 = __shfl_xor(A, 3);
        float cn = s1 * c[rr] + A * s2;   // valid on g0==0: f*c + i*g
        c[rr] = cn;
        hp.h[rr] = (f16)(s3 * tanh_(cn)); // valid on g0==0: o*tanh(cn)
    }
    return hp.u;
}

// Out-projection for timestep tOut: WG r covers (b,o) idx r*10..r*10+9;
// wave w handles p in {w, w+4, w+8} (p<10); 16 lanes per pair.
__device__ __forceinline__ void out_proj(const f16* __restrict__ h1pl,
                                         const float* __restrict__ Wo,
                                         const float* __restrict__ bo,
                                         float* __restrict__ out,
                                         int gb8, int tOut, int r, int w, int lane) {
    int slot = lane >> 4, kp = lane & 15;
    int p = slot * 4 + w;
    bool valid = (p < 10);
    int idx = valid ? (r * 10 + p) : 0;
    int b = idx / 20, o = idx % 20;
    float a = 0.f;
    if (valid) {
        const f16* hp = h1pl + kp * 256 + b * 32;         // [wg=kp][b][32u]
        const float* wo = Wo + (size_t)o * 512 + kp * 32;
#pragma unroll
        for (int k = 0; k < 32; k += 8) {
            f16x8 hv = ld16B(hp + k);
            float4 wa = *(const float4*)(wo + k);
            float4 wb = *(const float4*)(wo + k + 4);
            a += (float)hv[0] * wa.x + (float)hv[1] * wa.y +
                 (float)hv[2] * wa.z + (float)hv[3] * wa.w +
                 (float)hv[4] * wb.x + (float)hv[5] * wb.y +
                 (float)hv[6] * wb.z + (float)hv[7] * wb.w;
        }
    }
    a += __shfl_down(a, 8, 16);
    a += __shfl_down(a, 4, 16);
    a += __shfl_down(a, 2, 16);
    a += __shfl_down(a, 1, 16);
    if (valid && kp == 0)
        out[((size_t)(gb8 + b) * 1024 + tOut) * 20 + o] = sigm_(a + bo[o]);
}

// Zeros must be visible at the LLC -> sc0sc1 stores.
__global__ void zero_ws_kernel(unsigned* __restrict__ p, int ndw) {
    int i = blockIdx.x * blockDim.x + threadIdx.x;
    int stride = gridDim.x * blockDim.x;
    for (; i < ndw; i += stride)
        __hip_atomic_store(p + i, 0u, __ATOMIC_RELAXED, __HIP_MEMORY_SCOPE_SYSTEM);
}

__global__ __launch_bounds__(256, 1)
void lstm_persist(const float* __restrict__ x,
                  const float* __restrict__ Wx0, const float* __restrict__ bx0,
                  const float* __restrict__ Wh0,
                  const float* __restrict__ Wx1, const float* __restrict__ bx1,
                  const float* __restrict__ Wh1,
                  const float* __restrict__ Wo,  const float* __restrict__ bo,
                  float* __restrict__ out, char* __restrict__ ws) {
    __shared__ __align__(16) f16 tr[4][8][8];   // per-wave transpose scratch

    const int tid  = threadIdx.x, bid = blockIdx.x;
    const int g    = bid & 7;        // group
    const int rk   = bid >> 3;       // 0..31 within group
    const int role = rk >> 4;        // 0: layer-0 WG, 1: layer-1 WG
    const int r    = rk & 15;        // rank within role
    const int w    = tid >> 6;       // wave id = unit-block within WG
    const int lane = tid & 63;
    const int ln   = lane & 15;
    const int q    = lane >> 4;
    const int g0   = ln & 3;         // gate of this lane (i,f,g,o)
    const int uq   = ln >> 2;        // quad index (unit within half-block)
    const int bA   = ln & 7;         // A-frag batch row (8-15 duplicate)
    const int gb8  = g * 8;

    int* flag0 = (int*)(ws + WS_FLAG_OFF) + g * 128;   // 64 per-wave L0 flags
    int* flag1 = flag0 + 64;                            // 64 per-wave L1 flags
    f16* H0g = (f16*)(ws + WS_H0_OFF) + g * 16384;      // 4 planes x 4096 f16
    f16* H1g = (f16*)(ws + WS_H1_OFF) + g * 8192;       // 2 planes

    const int ubase = r * 32 + w * 8;                   // first unit of wave
    const float* bx = role ? bx1 : bx0;
    const float biasA = bx[(g0 << 9) + ubase + uq];
    const float biasB = bx[(g0 << 9) + ubase + uq + 4];

    // ---- persistent weight B-fragments ----------------------------------
    // Tile tau: n=ln <-> (unit ubase + (ln>>2) + tau*4, gate ln&3).
    // role0: W[tau*32 + kk], kk 0..16 (Wh0 K=512 + Wx0 pad-32 tail).
    // role1: W[tau*32 + kk], kk 0..15 = Wx1, 16..31 = Wh1.
    f16x8 W[64];
    {
        const int rowA = (g0 << 9) + ubase + uq;
#pragma unroll
        for (int tau = 0; tau < 2; ++tau) {
            const int row = rowA + tau * 4;
            if (role == 0) {
                const float* wh0r = Wh0 + (size_t)row * 512;
#pragma unroll
                for (int kk = 0; kk < 16; ++kk)
                    W[tau * 32 + kk] = pack8(wh0r + kk * 32 + q * 8);
                const float* wx0r = Wx0 + (size_t)row * 21;
                f16x8 f = {(_Float16)0, (_Float16)0, (_Float16)0, (_Float16)0,
                           (_Float16)0, (_Float16)0, (_Float16)0, (_Float16)0};
#pragma unroll
                for (int j = 0; j < 8; ++j) {
                    int kl = q * 8 + j;
                    if (kl < 21) f[j] = (f16)wx0r[kl];
                }
                W[tau * 32 + 16] = f;
            } else {
                const float* wx1r = Wx1 + (size_t)row * 512;
                const float* wh1r = Wh1 + (size_t)row * 512;
#pragma unroll
                for (int kk = 0; kk < 16; ++kk)
                    W[tau * 32 + kk] = pack8(wx1r + kk * 32 + q * 8);
#pragma unroll
                for (int kk = 16; kk < 32; ++kk)
                    W[tau * 32 + kk] = pack8(wh1r + (kk - 16) * 32 + q * 8);
            }
        }
    }

    float cA[4] = {0, 0, 0, 0}, cB[4] = {0, 0, 0, 0};   // cell state in regs

    if (role == 0) {
        // =================== layer-0 stage (wave-autonomous) ==============
        for (int t = 0; t < T_STEPS; ++t) {
            f16x8 xf = load_xfrag(x, gb8, t, bA, q);    // prefetch
            // need h0(t-1) complete and h0(t-4)'s plane consumed by L1
            wait2(flag0, t, flag1, t - 3, lane);
            const f16* hp = H0g + ((t + 3) & 3) * 4096; // h0(t-1)
            f32x4 a0 = {0, 0, 0, 0}, a1 = {0, 0, 0, 0};
            f16x8 F[16];
#pragma unroll
            for (int kk = 0; kk < 16; ++kk)
                F[kk] = ld16B(hp + kk * 256 + bA * 32 + q * 8);
#pragma unroll
            for (int kk = 0; kk < 16; ++kk) {
                a0 = __builtin_amdgcn_mfma_f32_16x16x32_f16(F[kk], W[kk], a0, 0, 0, 0);
                a1 = __builtin_amdgcn_mfma_f32_16x16x32_f16(F[kk], W[32 + kk], a1, 0, 0, 0);
            }
            a0 = __builtin_amdgcn_mfma_f32_16x16x32_f16(xf, W[16], a0, 0, 0, 0);
            a1 = __builtin_amdgcn_mfma_f32_16x16x32_f16(xf, W[48], a1, 0, 0, 0);

            u64 hA = act_tile(a0, biasA, cA, g0);
            u64 hB = act_tile(a1, biasB, cB, g0);
            if (g0 == 0 && q < 2) {      // valid batches live on q=0,1
                union { u64 u; f16 h[4]; } ua, ub; ua.u = hA; ub.u = hB;
#pragma unroll
                for (int rr = 0; rr < 4; ++rr) {
                    tr[w][q * 4 + rr][uq]     = ua.h[rr];
                    tr[w][q * 4 + rr][uq + 4] = ub.h[rr];
                }
            }
            asm volatile("s_waitcnt lgkmcnt(0)" ::: "memory");
            if (lane < 8) {
                f16x8 hv = *(const f16x8*)&tr[w][lane][0];
                st16B(H0g + (t & 3) * 4096 + r * 256 + lane * 32 + w * 8, hv);
            }
            asm volatile("s_waitcnt vmcnt(0)" ::: "memory");
            if (lane == 0)
                __hip_atomic_store(flag0 + r * 4 + w, t + 1,
                                   __ATOMIC_RELAXED, __HIP_MEMORY_SCOPE_SYSTEM);
        }
    } else {
        // =================== layer-1 stage (wave-autonomous) ==============
        for (int t = 0; t < T_STEPS; ++t) {
            // phase 1: h0(t) @ Wx1 (L0 runs up to 3 ahead -> wait short)
            wait1(flag0, t + 1, lane);
            const f16* h0pl = H0g + (t & 3) * 4096;
            f32x4 a0 = {0, 0, 0, 0}, a1 = {0, 0, 0, 0};
            f16x8 F[16];
#pragma unroll
            for (int kk = 0; kk < 16; ++kk)
                F[kk] = ld16B(h0pl + kk * 256 + bA * 32 + q * 8);
#pragma unroll
            for (int kk = 0; kk < 16; ++kk) {
                a0 = __builtin_amdgcn_mfma_f32_16x16x32_f16(F[kk], W[kk], a0, 0, 0, 0);
                a1 = __builtin_amdgcn_mfma_f32_16x16x32_f16(F[kk], W[32 + kk], a1, 0, 0, 0);
            }
            // phase 2: h1(t-1) @ Wh1 — the self-recurrence crossing
            wait1(flag1, t, lane);
            const f16* h1pl = H1g + ((t & 1) ^ 1) * 4096;
#pragma unroll
            for (int kk = 0; kk < 16; ++kk)
                F[kk] = ld16B(h1pl + kk * 256 + bA * 32 + q * 8);
#pragma unroll
            for (int kk = 0; kk < 16; ++kk) {
                a0 = __builtin_amdgcn_mfma_f32_16x16x32_f16(F[kk], W[16 + kk], a0, 0, 0, 0);
                a1 = __builtin_amdgcn_mfma_f32_16x16x32_f16(F[kk], W[48 + kk], a1, 0, 0, 0);
            }

            u64 hA = act_tile(a0, biasA, cA, g0);
            u64 hB = act_tile(a1, biasB, cB, g0);
            if (g0 == 0 && q < 2) {
                union { u64 u; f16 h[4]; } ua, ub; ua.u = hA; ub.u = hB;
#pragma unroll
                for (int rr = 0; rr < 4; ++rr) {
                    tr[w][q * 4 + rr][uq]     = ua.h[rr];
                    tr[w][q * 4 + rr][uq + 4] = ub.h[rr];
                }
            }
            asm volatile("s_waitcnt lgkmcnt(0)" ::: "memory");
            if (lane < 8) {
                f16x8 hv = *(const f16x8*)&tr[w][lane][0];
                st16B(H1g + (t & 1) * 4096 + r * 256 + lane * 32 + w * 8, hv);
            }
            // out-proj(t-1) BEFORE publish: its reads must retire before any
            // peer (gated on flag1 >= t+1) can overwrite h1(t-1)'s plane.
            if (t > 0)
                out_proj(h1pl, Wo, bo, out, gb8, t - 1, r, w, lane);
            asm volatile("s_waitcnt vmcnt(0)" ::: "memory");
            if (lane == 0)
                __hip_atomic_store(flag1 + r * 4 + w, t + 1,
                                   __ATOMIC_RELAXED, __HIP_MEMORY_SCOPE_SYSTEM);
        }
        // epilogue: out(T-1)
        wait1(flag1, T_STEPS, lane);
        out_proj(H1g + ((T_STEPS - 1) & 1) * 4096, Wo, bo, out,
                 gb8, T_STEPS - 1, r, w, lane);
    }
}

extern "C" void kernel_launch(void* const* d_in, const int* in_sizes, int n_in,
                              void* d_out, int out_size, void* d_ws, size_t ws_size,
                              hipStream_t stream) {
    const float* x   = (const float*)d_in[0];
    const float* Wx0 = (const float*)d_in[1];
    const float* bx0 = (const float*)d_in[2];
    const float* Wh0 = (const float*)d_in[3];
    const float* Wx1 = (const float*)d_in[4];
    const float* bx1 = (const float*)d_in[5];
    const float* Wh1 = (const float*)d_in[6];
    const float* Wo  = (const float*)d_in[7];
    const float* bo  = (const float*)d_in[8];
    float* out = (float*)d_out;
    char*  ws  = (char*)d_ws;

    if (ws_size < (size_t)WS_NEED) return;   // fail visibly (out stays poisoned)

    zero_ws_kernel<<<128, 256, 0, stream>>>((unsigned*)ws, WS_NEED / 4);
    lstm_persist<<<256, 256, 0, stream>>>(x, Wx0, bx0, Wh0, Wx1, bx1, Wh1,
                                          Wo, bo, out, ws);
}

// Round 10
// 15844.388 us; speedup vs baseline: 1.0413x; 1.0413x over previous
//
#include <hip/hip_runtime.h>

// ---------------------------------------------------------------------------
// Persistent 2-layer LSTM, MI355X. Round 10: wave-autonomous + COALESCED.
// 8 groups (blockIdx%8), 32 WGs/group: 16 L0-WGs (layer 0) + 16 L1-WGs
// (layer 1). Each wave owns 8 units x 4 gates (2 MFMA n-tiles); activation
// via 3 shfl_xor within lane-quads; cell state in registers; ZERO
// __syncthreads in the step loop (r9 core).
// r9 post-mortem fixes:
//  (1) h planes are [wg][wave][batch][8u] -> each wave publishes 128 B
//      CONTIGUOUS (r9's 16B-at-64B-stride write-through caused 4x HBM write
//      amplification: WRITE_SIZE 562 MB).
//  (2) 84 KB LDS pad restored -> exactly 1 WG/CU (r9 dropped it; doubled-up
//      CUs made the lock-step group run at straggler speed, 16-57 ms).
// A-frags load directly global->VGPR as contiguous 16 B bypass loads.
// Protocol: relaxed sc0sc1 LLC ops, per-wave monotone flags, h0 depth-4 /
// h1 depth-2, out-proj before publish (proven r8/r9).
// ---------------------------------------------------------------------------

#define T_STEPS 1024
#define WS_FLAG_OFF 0                     // 8 g * 128 ints = 4 KB
#define WS_H0_OFF  4096                   // 8 g * 4 planes * 8 KB
#define WS_H1_OFF  (4096 + 8*4*8192)      // 8 g * 2 planes * 8 KB
#define WS_NEED    (WS_H1_OFF + 8*2*8192) // 397312 B

typedef _Float16 f16;
typedef _Float16 f16x8 __attribute__((ext_vector_type(8)));
typedef float    f32x4 __attribute__((ext_vector_type(4)));
typedef unsigned long long u64;

__device__ __forceinline__ float sigm_(float x) {
    x = fminf(fmaxf(x, -30.f), 30.f);
    return 1.f / (1.f + __expf(-x));
}
__device__ __forceinline__ float tanh_(float x) {
    x = fminf(fmaxf(x, -15.f), 15.f);
    float e = __expf(-2.f * x);
    return (1.f - e) / (1.f + e);
}

__device__ __forceinline__ u64 ldg64(const u64* p) {
    return __hip_atomic_load(p, __ATOMIC_RELAXED, __HIP_MEMORY_SCOPE_SYSTEM);
}
__device__ __forceinline__ void stg64(u64* p, u64 v) {
    __hip_atomic_store(p, v, __ATOMIC_RELAXED, __HIP_MEMORY_SCOPE_SYSTEM);
}
// 16 B bypass load/store as two u64 system-scope ops (LLC-coherent).
__device__ __forceinline__ f16x8 ld16B(const f16* p) {
    union { u64 u[2]; f16x8 v; } cv;
    cv.u[0] = ldg64((const u64*)p);
    cv.u[1] = ldg64((const u64*)p + 1);
    return cv.v;
}
__device__ __forceinline__ void st16B(f16* p, f16x8 v) {
    union { u64 u[2]; f16x8 x; } cv; cv.x = v;
    stg64((u64*)p, cv.u[0]);
    stg64((u64*)p + 1, cv.u[1]);
}

__device__ __forceinline__ f16x8 pack8(const float* p) {
    float4 a = *(const float4*)p, b = *(const float4*)(p + 4);
    f16x8 f;
    f[0] = (f16)a.x; f[1] = (f16)a.y; f[2] = (f16)a.z; f[3] = (f16)a.w;
    f[4] = (f16)b.x; f[5] = (f16)b.y; f[6] = (f16)b.z; f[7] = (f16)b.w;
    return f;
}

// Poll 64 per-wave flags: lane l loads flag[l]; single __all vote.
__device__ __forceinline__ void wait1(const int* f, int t, int lane) {
    int spins = 0;
    for (;;) {
        int a = __hip_atomic_load(f + lane, __ATOMIC_RELAXED,
                                  __HIP_MEMORY_SCOPE_SYSTEM);
        if (__all(a >= t)) break;
        __builtin_amdgcn_s_sleep(1);
        if (++spins > (1 << 20)) break;   // anti-hang safety valve
    }
}
__device__ __forceinline__ void wait2(const int* fA, int tA,
                                      const int* fB, int tB, int lane) {
    int spins = 0;
    for (;;) {
        int a = __hip_atomic_load(fA + lane, __ATOMIC_RELAXED,
                                  __HIP_MEMORY_SCOPE_SYSTEM);
        int b = __hip_atomic_load(fB + lane, __ATOMIC_RELAXED,
                                  __HIP_MEMORY_SCOPE_SYSTEM);
        if (__all((a >= tA) && (b >= tB))) break;
        __builtin_amdgcn_s_sleep(1);
        if (++spins > (1 << 20)) break;
    }
}

// x A-fragment for step t, batch row b (duplicated for lanes 8-15).
__device__ __forceinline__ f16x8 load_xfrag(const float* __restrict__ x,
                                            int gb8, int t, int b, int q) {
    f16x8 f = {(_Float16)0, (_Float16)0, (_Float16)0, (_Float16)0,
               (_Float16)0, (_Float16)0, (_Float16)0, (_Float16)0};
    const float* xp = x + ((size_t)(gb8 + b) * 1024 + t) * 21;
#pragma unroll
    for (int j = 0; j < 8; ++j) {
        int kl = q * 8 + j;
        if (kl < 21) f[j] = (f16)xp[kl];
    }
    return f;
}

// Activation for one n-tile: each lane activates ITS gate (g0) of its quad's
// unit, then 3 quad shuffles assemble cn/h on the g0==0 lane.
// g0: 0=i(sigm) 1=f(sigm) 2=g(tanh) 3=o(sigm).
__device__ __forceinline__ u64 act_tile(f32x4 acc, float bias, float* c, int g0) {
    union { f16 h[4]; u64 u; } hp;
#pragma unroll
    for (int rr = 0; rr < 4; ++rr) {
        float pre = acc[rr] + bias;
        float A  = (g0 == 2) ? tanh_(pre) : sigm_(pre);
        float s1 = __shfl_xor(A, 1);
        float s2 = __shfl_xor(A, 2);
        float s3 = __shfl_xor(A, 3);
        float cn = s1 * c[rr] + A * s2;   // valid on g0==0: f*c + i*g
        c[rr] = cn;
        hp.h[rr] = (f16)(s3 * tanh_(cn)); // valid on g0==0: o*tanh(cn)
    }
    return hp.u;
}

// Out-projection for timestep tOut. Plane layout [wg kp][wv][b][8u]:
// unit k = kp*32 + wv*8 + j lives at f16 offset kp*256 + wv*64 + b*8 + j.
__device__ __forceinline__ void out_proj(const f16* __restrict__ h1pl,
                                         const float* __restrict__ Wo,
                                         const float* __restrict__ bo,
                                         float* __restrict__ out,
                                         int gb8, int tOut, int r, int w, int lane) {
    int slot = lane >> 4, kp = lane & 15;
    int p = slot * 4 + w;
    bool valid = (p < 10);
    int idx = valid ? (r * 10 + p) : 0;
    int b = idx / 20, o = idx % 20;
    float a = 0.f;
    if (valid) {
        const f16* hp = h1pl + kp * 256 + b * 8;
        const float* wo = Wo + (size_t)o * 512 + kp * 32;
#pragma unroll
        for (int wv = 0; wv < 4; ++wv) {
            f16x8 hv = ld16B(hp + wv * 64);
            float4 wa = *(const float4*)(wo + wv * 8);
            float4 wb = *(const float4*)(wo + wv * 8 + 4);
            a += (float)hv[0] * wa.x + (float)hv[1] * wa.y +
                 (float)hv[2] * wa.z + (float)hv[3] * wa.w +
                 (float)hv[4] * wb.x + (float)hv[5] * wb.y +
                 (float)hv[6] * wb.z + (float)hv[7] * wb.w;
        }
    }
    a += __shfl_down(a, 8, 16);
    a += __shfl_down(a, 4, 16);
    a += __shfl_down(a, 2, 16);
    a += __shfl_down(a, 1, 16);
    if (valid && kp == 0)
        out[((size_t)(gb8 + b) * 1024 + tOut) * 20 + o] = sigm_(a + bo[o]);
}

// Zeros must be visible at the LLC -> sc0sc1 stores.
__global__ void zero_ws_kernel(unsigned* __restrict__ p, int ndw) {
    int i = blockIdx.x * blockDim.x + threadIdx.x;
    int stride = gridDim.x * blockDim.x;
    for (; i < ndw; i += stride)
        __hip_atomic_store(p + i, 0u, __ATOMIC_RELAXED, __HIP_MEMORY_SCOPE_SYSTEM);
}

__global__ __launch_bounds__(256, 1)
void lstm_persist(const float* __restrict__ x,
                  const float* __restrict__ Wx0, const float* __restrict__ bx0,
                  const float* __restrict__ Wh0,
                  const float* __restrict__ Wx1, const float* __restrict__ bx1,
                  const float* __restrict__ Wh1,
                  const float* __restrict__ Wo,  const float* __restrict__ bo,
                  float* __restrict__ out, char* __restrict__ ws) {
    struct SM {
        __align__(16) f16 tr[4][8][8];   // per-wave transpose scratch
        char pad[84 * 1024];             // force exactly 1 WG/CU (2x84K>160K)
    };
    __shared__ SM sm;
    const int tid  = threadIdx.x, bid = blockIdx.x;
    if (tid == 0x00FFFFFFu) sm.pad[0] = 1;       // keep pad alive

    const int g    = bid & 7;        // group
    const int rk   = bid >> 3;       // 0..31 within group
    const int role = rk >> 4;        // 0: layer-0 WG, 1: layer-1 WG
    const int r    = rk & 15;        // rank within role
    const int w    = tid >> 6;       // wave id = unit-block within WG
    const int lane = tid & 63;
    const int ln   = lane & 15;
    const int q    = lane >> 4;
    const int g0   = ln & 3;         // gate of this lane (i,f,g,o)
    const int uq   = ln >> 2;        // unit quad index within tile
    const int bA   = ln & 7;         // A-frag batch row (8-15 duplicate)
    const int gb8  = g * 8;

    int* flag0 = (int*)(ws + WS_FLAG_OFF) + g * 128;   // 64 per-wave L0 flags
    int* flag1 = flag0 + 64;                            // 64 per-wave L1 flags
    f16* H0g = (f16*)(ws + WS_H0_OFF) + g * 16384;      // 4 planes x 4096 f16
    f16* H1g = (f16*)(ws + WS_H1_OFF) + g * 8192;       // 2 planes

    const int ubase = r * 32 + w * 8;                   // first unit of wave
    const float* bx = role ? bx1 : bx0;
    const float biasA = bx[(g0 << 9) + ubase + uq];
    const float biasB = bx[(g0 << 9) + ubase + uq + 4];

    // ---- persistent weight B-fragments (k-order = identity unit order) ---
    f16x8 W[64];
    {
        const int rowA = (g0 << 9) + ubase + uq;
#pragma unroll
        for (int tau = 0; tau < 2; ++tau) {
            const int row = rowA + tau * 4;
            if (role == 0) {
                const float* wh0r = Wh0 + (size_t)row * 512;
#pragma unroll
                for (int kk = 0; kk < 16; ++kk)
                    W[tau * 32 + kk] = pack8(wh0r + kk * 32 + q * 8);
                const float* wx0r = Wx0 + (size_t)row * 21;
                f16x8 f = {(_Float16)0, (_Float16)0, (_Float16)0, (_Float16)0,
                           (_Float16)0, (_Float16)0, (_Float16)0, (_Float16)0};
#pragma unroll
                for (int j = 0; j < 8; ++j) {
                    int kl = q * 8 + j;
                    if (kl < 21) f[j] = (f16)wx0r[kl];
                }
                W[tau * 32 + 16] = f;
            } else {
                const float* wx1r = Wx1 + (size_t)row * 512;
                const float* wh1r = Wh1 + (size_t)row * 512;
#pragma unroll
                for (int kk = 0; kk < 16; ++kk)
                    W[tau * 32 + kk] = pack8(wx1r + kk * 32 + q * 8);
#pragma unroll
                for (int kk = 16; kk < 32; ++kk)
                    W[tau * 32 + kk] = pack8(wh1r + (kk - 16) * 32 + q * 8);
            }
        }
    }

    float cA[4] = {0, 0, 0, 0}, cB[4] = {0, 0, 0, 0};   // cell state in regs
    // A-frag address in plane: k-block kk, quad q, batch bA ->
    //   [wg=kk][wv=q][b=bA][8u] = f16 offset kk*256 + q*64 + bA*8  (16 B).
    const int fragOff = q * 64 + bA * 8;
    // Publish address: [wg=r][wv=w][b=lane][8u] -> r*256 + w*64 + lane*8.
    // Lanes 0-7 write 16 B each at 16 B stride = 128 B CONTIGUOUS.
    const int pubOff = r * 256 + w * 64;

    if (role == 0) {
        // =================== layer-0 stage (wave-autonomous) ==============
        for (int t = 0; t < T_STEPS; ++t) {
            f16x8 xf = load_xfrag(x, gb8, t, bA, q);    // prefetch
            wait2(flag0, t, flag1, t - 3, lane);        // h0(t-1) + backpressure
            const f16* hp = H0g + ((t + 3) & 3) * 4096; // h0(t-1)
            f32x4 a0 = {0, 0, 0, 0}, a1 = {0, 0, 0, 0};
            f16x8 F[16];
#pragma unroll
            for (int kk = 0; kk < 16; ++kk)
                F[kk] = ld16B(hp + kk * 256 + fragOff);
#pragma unroll
            for (int kk = 0; kk < 16; ++kk) {
                a0 = __builtin_amdgcn_mfma_f32_16x16x32_f16(F[kk], W[kk], a0, 0, 0, 0);
                a1 = __builtin_amdgcn_mfma_f32_16x16x32_f16(F[kk], W[32 + kk], a1, 0, 0, 0);
            }
            a0 = __builtin_amdgcn_mfma_f32_16x16x32_f16(xf, W[16], a0, 0, 0, 0);
            a1 = __builtin_amdgcn_mfma_f32_16x16x32_f16(xf, W[48], a1, 0, 0, 0);

            u64 hA = act_tile(a0, biasA, cA, g0);
            u64 hB = act_tile(a1, biasB, cB, g0);
            if (g0 == 0 && q < 2) {      // valid batches live on q=0,1
                union { u64 u; f16 h[4]; } ua, ub; ua.u = hA; ub.u = hB;
#pragma unroll
                for (int rr = 0; rr < 4; ++rr) {
                    sm.tr[w][q * 4 + rr][uq]     = ua.h[rr];
                    sm.tr[w][q * 4 + rr][uq + 4] = ub.h[rr];
                }
            }
            asm volatile("s_waitcnt lgkmcnt(0)" ::: "memory");
            if (lane < 8) {
                f16x8 hv = *(const f16x8*)&sm.tr[w][lane][0];
                st16B(H0g + (t & 3) * 4096 + pubOff + lane * 8, hv);
            }
            asm volatile("s_waitcnt vmcnt(0)" ::: "memory");
            if (lane == 0)
                __hip_atomic_store(flag0 + r * 4 + w, t + 1,
                                   __ATOMIC_RELAXED, __HIP_MEMORY_SCOPE_SYSTEM);
        }
    } else {
        // =================== layer-1 stage (wave-autonomous) ==============
        for (int t = 0; t < T_STEPS; ++t) {
            // phase 1: h0(t) @ Wx1 (L0 runs up to 3 ahead -> wait short)
            wait1(flag0, t + 1, lane);
            const f16* h0pl = H0g + (t & 3) * 4096;
            f32x4 a0 = {0, 0, 0, 0}, a1 = {0, 0, 0, 0};
            f16x8 F[16];
#pragma unroll
            for (int kk = 0; kk < 16; ++kk)
                F[kk] = ld16B(h0pl + kk * 256 + fragOff);
#pragma unroll
            for (int kk = 0; kk < 16; ++kk) {
                a0 = __builtin_amdgcn_mfma_f32_16x16x32_f16(F[kk], W[kk], a0, 0, 0, 0);
                a1 = __builtin_amdgcn_mfma_f32_16x16x32_f16(F[kk], W[32 + kk], a1, 0, 0, 0);
            }
            // phase 2: h1(t-1) @ Wh1 — the self-recurrence crossing
            wait1(flag1, t, lane);
            const f16* h1pl = H1g + ((t & 1) ^ 1) * 4096;
#pragma unroll
            for (int kk = 0; kk < 16; ++kk)
                F[kk] = ld16B(h1pl + kk * 256 + fragOff);
#pragma unroll
            for (int kk = 0; kk < 16; ++kk) {
                a0 = __builtin_amdgcn_mfma_f32_16x16x32_f16(F[kk], W[16 + kk], a0, 0, 0, 0);
                a1 = __builtin_amdgcn_mfma_f32_16x16x32_f16(F[kk], W[48 + kk], a1, 0, 0, 0);
            }

            u64 hA = act_tile(a0, biasA, cA, g0);
            u64 hB = act_tile(a1, biasB, cB, g0);
            if (g0 == 0 && q < 2) {
                union { u64 u; f16 h[4]; } ua, ub; ua.u = hA; ub.u = hB;
#pragma unroll
                for (int rr = 0; rr < 4; ++rr) {
                    sm.tr[w][q * 4 + rr][uq]     = ua.h[rr];
                    sm.tr[w][q * 4 + rr][uq + 4] = ub.h[rr];
                }
            }
            asm volatile("s_waitcnt lgkmcnt(0)" ::: "memory");
            if (lane < 8) {
                f16x8 hv = *(const f16x8*)&sm.tr[w][lane][0];
                st16B(H1g + (t & 1) * 4096 + pubOff + lane * 8, hv);
            }
            // out-proj(t-1) BEFORE publish: its reads must retire before any
            // peer (gated on flag1 >= t+1) can overwrite h1(t-1)'s plane.
            if (t > 0)
                out_proj(h1pl, Wo, bo, out, gb8, t - 1, r, w, lane);
            asm volatile("s_waitcnt vmcnt(0)" ::: "memory");
            if (lane == 0)
                __hip_atomic_store(flag1 + r * 4 + w, t + 1,
                                   __ATOMIC_RELAXED, __HIP_MEMORY_SCOPE_SYSTEM);
        }
        // epilogue: out(T-1)
        wait1(flag1, T_STEPS, lane);
        out_proj(H1g + ((T_STEPS - 1) & 1) * 4096, Wo, bo, out,
                 gb8, T_STEPS - 1, r, w, lane);
    }
}

extern "C" void kernel_launch(void* const* d_in, const int* in_sizes, int n_in,
                              void* d_out, int out_size, void* d_ws, size_t ws_size,
                              hipStream_t stream) {
    const float* x   = (const float*)d_in[0];
    const float* Wx0 = (const float*)d_in[1];
    const float* bx0 = (const float*)d_in[2];
    const float* Wh0 = (const float*)d_in[3];
    const float* Wx1 = (const float*)d_in[4];
    const float* bx1 = (const float*)d_in[5];
    const float* Wh1 = (const float*)d_in[6];
    const float* Wo  = (const float*)d_in[7];
    const float* bo  = (const float*)d_in[8];
    float* out = (float*)d_out;
    char*  ws  = (char*)d_ws;

    if (ws_size < (size_t)WS_NEED) return;   // fail visibly (out stays poisoned)

    zero_ws_kernel<<<128, 256, 0, stream>>>((unsigned*)ws, WS_NEED / 4);
    lstm_persist<<<256, 256, 0, stream>>>(x, Wx0, bx0, Wh0, Wx1, bx1, Wh1,
                                          Wo, bo, out, ws);
}

// Round 11
// 4820.155 us; speedup vs baseline: 3.4229x; 3.2871x over previous
//
#include <hip/hip_runtime.h>

// ---------------------------------------------------------------------------
// Persistent 2-layer LSTM, MI355X. Round 11 = proven Round-8 base + WAVE-0-ONLY
// POLLING. r9/r10 post-mortem: all-thread system-scope polling saturates the
// LLC slices holding the flags; the publisher's flag store queues behind the
// poll reads -> multi-us, placement-dependent detect latency (the 15-56 ms
// variance). Fix: only wave 0 polls; waves 1-3 wait at __syncthreads (local).
// Everything else is the r8 structure verbatim: 16 L0-WGs + 16 L1-WGs per
// group, weights in VGPRs, h0 depth-4 / h1 depth-2 planes, relaxed sc0sc1
// LLC ops, per-WG monotone flags, LDS-staged A-fragments, 1 WG/CU pad.
// ---------------------------------------------------------------------------

#define T_STEPS 1024
#define WS_FLAG_OFF 0                     // 8 groups * 128 ints (512 B apart)
#define WS_H0_OFF  4096                   // [8 g][4 depth][16 wg][8 b][32 u] f16
#define WS_H1_OFF  (4096 + 8*4*8192)      // [8 g][2 depth][...]
#define WS_NEED    (WS_H1_OFF + 8*2*8192) // 397312 B (r9/r10 size, known-good)

typedef _Float16 f16;
typedef _Float16 f16x8 __attribute__((ext_vector_type(8)));
typedef float    f32x4 __attribute__((ext_vector_type(4)));
typedef unsigned long long u64;

#define HP_STRIDE 520   // padded LDS plane row stride (f16)

__device__ __forceinline__ float sigm_(float x) {
    x = fminf(fmaxf(x, -30.f), 30.f);
    return 1.f / (1.f + __expf(-x));
}
__device__ __forceinline__ float tanh_(float x) {
    x = fminf(fmaxf(x, -15.f), 15.f);
    float e = __expf(-2.f * x);
    return (1.f - e) / (1.f + e);
}

// A-fragment for 16x16x32 f16 MFMA from a padded LDS plane.
// A[m=lane&15][k=(lane>>4)*8+j]; m = batch (0..7 valid, 8..15 -> zeros).
__device__ __forceinline__ f16x8 afrag_lds(const f16* __restrict__ hp, int kbase,
                                           int b, int q) {
    if (b < 8) {
        return *(const f16x8*)(hp + b * HP_STRIDE + kbase + q * 8);
    }
    f16x8 z = {(_Float16)0, (_Float16)0, (_Float16)0, (_Float16)0,
               (_Float16)0, (_Float16)0, (_Float16)0, (_Float16)0};
    return z;
}

__device__ __forceinline__ f16x8 pack8(const float* p) {
    float4 a = *(const float4*)p, b = *(const float4*)(p + 4);
    f16x8 f;
    f[0] = (f16)a.x; f[1] = (f16)a.y; f[2] = (f16)a.z; f[3] = (f16)a.w;
    f[4] = (f16)b.x; f[5] = (f16)b.y; f[6] = (f16)b.z; f[7] = (f16)b.w;
    return f;
}

// Wait until all 16 flag0 >= t0 AND all 16 flag1 >= t1.
// CALLED BY WAVE 0 ONLY (poll-pressure fix): lanes 0-15 load flag0,
// 16-31 flag1, 32-63 duplicate; single __all vote; relaxed system loads.
__device__ __forceinline__ void wait_flags(const int* f0, int t0,
                                           const int* f1, int t1, int lane) {
    const int* p = (lane & 16) ? (f1 + (lane & 15)) : (f0 + (lane & 15));
    const int tgt = (lane & 16) ? t1 : t0;
    int spins = 0;
    for (;;) {
        int v = __hip_atomic_load(p, __ATOMIC_RELAXED, __HIP_MEMORY_SCOPE_SYSTEM);
        if (__all(v >= tgt)) break;
        __builtin_amdgcn_s_sleep(1);
        if (++spins > (1 << 20)) break;   // anti-hang safety valve
    }
}

// Stage one 8 KB h-plane ([16 wg][8 b][32 u] f16, WG-major global) into the
// padded LDS [batch][unit 0..511] plane. u64 i: wg=i>>6, b=(i>>3)&7, j=i&7.
__device__ __forceinline__ void stage_plane(const f16* __restrict__ gp,
                                            f16* __restrict__ dst, int tid) {
    const u64* g8 = (const u64*)gp;
    u64 v[4];
#pragma unroll
    for (int jj = 0; jj < 4; ++jj)
        v[jj] = __hip_atomic_load(g8 + jj * 256 + tid, __ATOMIC_RELAXED,
                                  __HIP_MEMORY_SCOPE_SYSTEM);
#pragma unroll
    for (int jj = 0; jj < 4; ++jj) {
        int i = jj * 256 + tid;
        int wg = i >> 6, b = (i >> 3) & 7, j = i & 7;
        *(u64*)(dst + b * HP_STRIDE + wg * 32 + j * 4) = v[jj];
    }
}

// x A-fragment for step t.
__device__ __forceinline__ f16x8 load_xfrag(const float* __restrict__ x,
                                            int gb8, int t, int ln, int q) {
    f16x8 f = {(_Float16)0, (_Float16)0, (_Float16)0, (_Float16)0,
               (_Float16)0, (_Float16)0, (_Float16)0, (_Float16)0};
    if (ln < 8 && t < T_STEPS) {
        const float* xp = x + ((size_t)(gb8 + ln) * 1024 + t) * 21;
#pragma unroll
        for (int j = 0; j < 8; ++j) {
            int kl = q * 8 + j;
            if (kl < 21) f[j] = (f16)xp[kl];
        }
    }
    return f;
}

// Zeros must be visible at the LLC -> sc0sc1 stores.
__global__ void zero_ws_kernel(unsigned* __restrict__ p, int ndw) {
    int i = blockIdx.x * blockDim.x + threadIdx.x;
    int stride = gridDim.x * blockDim.x;
    for (; i < ndw; i += stride)
        __hip_atomic_store(p + i, 0u, __ATOMIC_RELAXED, __HIP_MEMORY_SCOPE_SYSTEM);
}

__global__ __launch_bounds__(256, 1)
void lstm_persist(const float* __restrict__ x,
                  const float* __restrict__ Wx0, const float* __restrict__ bx0,
                  const float* __restrict__ Wh0,
                  const float* __restrict__ Wx1, const float* __restrict__ bx1,
                  const float* __restrict__ Wh1,
                  const float* __restrict__ Wo,  const float* __restrict__ bo,
                  float* __restrict__ out, char* __restrict__ ws) {
    struct SM {
        float g[4][8][33];                       // gate tiles [gate][b][u0..31]+pad
        float c[8][32];                          // this WG's cell state
        float bias[4][32];                       // this WG's bias slice
        __align__(8)  f16 hout[8][32];           // activation -> packed store
        __align__(16) f16 planeA[8 * HP_STRIDE]; // h0 plane
        __align__(16) f16 planeB[8 * HP_STRIDE]; // h1 plane (L1 only)
        char  pad[60 * 1024];                    // force 1 WG/CU
    };
    __shared__ SM sm;
    const int tid = threadIdx.x;
    if (tid == 0x00FFFFFFu) sm.pad[0] = 1;       // keep pad alive

    const int bid  = blockIdx.x;
    const int g    = bid & 7;        // group (XCD-affine under round-robin)
    const int rk   = bid >> 3;       // 0..31 within group
    const int role = rk >> 4;        // 0: layer-0 WG, 1: layer-1 WG
    const int r    = rk & 15;        // rank within role
    const int w    = tid >> 6;       // wave id = gate type (i,f,g,o)
    const int lane = tid & 63;
    const int ln   = lane & 15;
    const int q    = lane >> 4;
    const int gb8  = g * 8;

    int* barb  = (int*)(ws + WS_FLAG_OFF) + g * 128;  // 512 B per group
    int* flag0 = barb;               // 16 per-L0-WG monotone step flags
    int* flag1 = barb + 64;          // 16 per-L1-WG flags (separate line)
    f16* H0g = (f16*)(ws + WS_H0_OFF) + g * 16384;  // 4 depth planes
    f16* H1g = (f16*)(ws + WS_H1_OFF) + g * 8192;   // 2 depth planes

    // ---- LDS init -------------------------------------------------------
    ((float*)sm.c)[tid] = 0.f;                   // 8*32 = 256 floats
    if (tid < 128) {
        int gate = tid >> 5, u = tid & 31;
        const float* bx = role ? bx1 : bx0;
        sm.bias[gate][u] = bx[(gate << 9) + (r << 5) + u];
    }

    // ---- persistent weight fragments in registers -----------------------
    // W[ ]: role 0 -> W[tau*17+kk] (K=544: Wh0|Wx0pad), tau in {0,1} n-tiles.
    //       role 1 -> W[tau*32+kk] (K=1024: Wx1|Wh1).
    f16x8 W[64];
    if (role == 0) {
#pragma unroll
        for (int tau = 0; tau < 2; ++tau) {
            const int rw = (w << 9) + (r << 5) + tau * 16 + ln;
            const float* wh0r = Wh0 + (size_t)rw * 512;
#pragma unroll
            for (int kk = 0; kk < 16; ++kk)
                W[tau * 17 + kk] = pack8(wh0r + kk * 32 + q * 8);
            const float* wx0r = Wx0 + (size_t)rw * 21;
            f16x8 f = {(_Float16)0, (_Float16)0, (_Float16)0, (_Float16)0,
                       (_Float16)0, (_Float16)0, (_Float16)0, (_Float16)0};
#pragma unroll
            for (int j = 0; j < 8; ++j) {
                int kl = q * 8 + j;
                if (kl < 21) f[j] = (f16)wx0r[kl];
            }
            W[tau * 17 + 16] = f;
        }
    } else {
#pragma unroll
        for (int tau = 0; tau < 2; ++tau) {
            const int rw = (w << 9) + (r << 5) + tau * 16 + ln;
            const float* wx1r = Wx1 + (size_t)rw * 512;
            const float* wh1r = Wh1 + (size_t)rw * 512;
#pragma unroll
            for (int kk = 0; kk < 16; ++kk)
                W[tau * 32 + kk] = pack8(wx1r + kk * 32 + q * 8);
#pragma unroll
            for (int kk = 16; kk < 32; ++kk)
                W[tau * 32 + kk] = pack8(wh1r + (kk - 16) * 32 + q * 8);
        }
    }
    __syncthreads();

    if (role == 0) {
        // =================== layer-0 pipeline stage =======================
        // Writes h0(t) -> plane t&3. Waits flag1 >= t-3 so h0(t-4)'s plane is
        // consumed before overwrite; runs up to 3 steps ahead of L1.
        for (int t = 0; t < T_STEPS; ++t) {
            const int wr = t & 3, rd = (t + 3) & 3;
            f16x8 xf = load_xfrag(x, gb8, t, ln, q);   // prefetch before wait
            if (tid < 64) wait_flags(flag0, t, flag1, t - 3, lane);
            __syncthreads();                           // release waves 1-3
            stage_plane(H0g + rd * 4096, sm.planeA, tid);
            __syncthreads();

            f32x4 a0 = {0, 0, 0, 0}, a1 = {0, 0, 0, 0};
#pragma unroll
            for (int kk = 0; kk < 16; ++kk) {
                f16x8 A = afrag_lds(sm.planeA, kk * 32, ln, q);
                a0 = __builtin_amdgcn_mfma_f32_16x16x32_f16(A, W[kk], a0, 0, 0, 0);
                a1 = __builtin_amdgcn_mfma_f32_16x16x32_f16(A, W[17 + kk], a1, 0, 0, 0);
            }
            a0 = __builtin_amdgcn_mfma_f32_16x16x32_f16(xf, W[16], a0, 0, 0, 0);
            a1 = __builtin_amdgcn_mfma_f32_16x16x32_f16(xf, W[33], a1, 0, 0, 0);
            if (q < 2) {
#pragma unroll
                for (int r4 = 0; r4 < 4; ++r4) {
                    sm.g[w][q * 4 + r4][ln] = a0[r4];
                    sm.g[w][q * 4 + r4][16 + ln] = a1[r4];
                }
            }
            __syncthreads();
            {   // activation: 8 batches x 32 units = 256 threads
                int b = tid >> 5, u = tid & 31;
                float gi = sm.g[0][b][u] + sm.bias[0][u];
                float gf = sm.g[1][b][u] + sm.bias[1][u];
                float gg = sm.g[2][b][u] + sm.bias[2][u];
                float go = sm.g[3][b][u] + sm.bias[3][u];
                float iv = sigm_(gi), fv = sigm_(gf), gv = tanh_(gg), ov = sigm_(go);
                float c = sm.c[b][u];
                float cn = fv * c + iv * gv;
                sm.c[b][u] = cn;
                sm.hout[b][u] = (f16)(ov * tanh_(cn));
            }
            __syncthreads();
            if (tid < 64) {   // 512 B contiguous WG slice, wave-0 only
                int b = tid >> 3, j = tid & 7;
                u64 v = *(const u64*)&sm.hout[b][j * 4];
                __hip_atomic_store((u64*)(H0g + wr * 4096 + (r << 8) + (b << 5) + (j << 2)),
                                   v, __ATOMIC_RELAXED, __HIP_MEMORY_SCOPE_SYSTEM);
                asm volatile("s_waitcnt vmcnt(0)" ::: "memory");
                if (tid == 0)
                    __hip_atomic_store(flag0 + r, t + 1, __ATOMIC_RELAXED,
                                       __HIP_MEMORY_SCOPE_SYSTEM);
            }
        }
    } else {
        // =================== layer-1 pipeline stage =======================
        for (int t = 0; t < T_STEPS; ++t) {
            const int wr = t & 1, rd = wr ^ 1;

            // ---- h0(t) half first (L0 runs ahead -> wait usually instant) -
            if (tid < 64) wait_flags(flag0, t + 1, flag1, t - 1000000000, lane);
            __syncthreads();
            stage_plane(H0g + (t & 3) * 4096, sm.planeA, tid);
            __syncthreads();
            f32x4 a0 = {0, 0, 0, 0}, a1 = {0, 0, 0, 0};
#pragma unroll
            for (int kk = 0; kk < 16; ++kk) {
                f16x8 A = afrag_lds(sm.planeA, kk * 32, ln, q);
                a0 = __builtin_amdgcn_mfma_f32_16x16x32_f16(A, W[kk], a0, 0, 0, 0);
                a1 = __builtin_amdgcn_mfma_f32_16x16x32_f16(A, W[32 + kk], a1, 0, 0, 0);
            }

            // ---- h1(t-1) half: the self-recurrence crossing ---------------
            if (tid < 64) wait_flags(flag1, t, flag1, t, lane);
            __syncthreads();
            stage_plane(H1g + rd * 4096, sm.planeB, tid);
            __syncthreads();
#pragma unroll
            for (int kk = 16; kk < 32; ++kk) {
                f16x8 A = afrag_lds(sm.planeB, (kk - 16) * 32, ln, q);
                a0 = __builtin_amdgcn_mfma_f32_16x16x32_f16(A, W[kk], a0, 0, 0, 0);
                a1 = __builtin_amdgcn_mfma_f32_16x16x32_f16(A, W[32 + kk], a1, 0, 0, 0);
            }
            if (q < 2) {
#pragma unroll
                for (int r4 = 0; r4 < 4; ++r4) {
                    sm.g[w][q * 4 + r4][ln] = a0[r4];
                    sm.g[w][q * 4 + r4][16 + ln] = a1[r4];
                }
            }
            __syncthreads();
            {
                int b = tid >> 5, u = tid & 31;
                float gi = sm.g[0][b][u] + sm.bias[0][u];
                float gf = sm.g[1][b][u] + sm.bias[1][u];
                float gg = sm.g[2][b][u] + sm.bias[2][u];
                float go = sm.g[3][b][u] + sm.bias[3][u];
                float iv = sigm_(gi), fv = sigm_(gf), gv = tanh_(gg), ov = sigm_(go);
                float c = sm.c[b][u];
                float cn = fv * c + iv * gv;
                sm.c[b][u] = cn;
                sm.hout[b][u] = (f16)(ov * tanh_(cn));
            }
            __syncthreads();
            if (tid < 64) {
                int b = tid >> 3, j = tid & 7;
                u64 v = *(const u64*)&sm.hout[b][j * 4];
                __hip_atomic_store((u64*)(H1g + wr * 4096 + (r << 8) + (b << 5) + (j << 2)),
                                   v, __ATOMIC_RELAXED, __HIP_MEMORY_SCOPE_SYSTEM);
                asm volatile("s_waitcnt vmcnt(0)" ::: "memory");
                if (tid == 0)
                    __hip_atomic_store(flag1 + r, t + 1, __ATOMIC_RELAXED,
                                       __HIP_MEMORY_SCOPE_SYSTEM);
            }

            // ---- out-proj(t-1) AFTER publish, from LDS planeB (off path).
            // Safe: next stage of planeB happens after the next wait's
            // __syncthreads, which orders it after these reads.
            if (t > 0) {
                int p = tid >> 4, kp = tid & 15;
                int valid = (p < 10);
                int idx = r * 10 + p;
                int b = valid ? idx / 20 : 0, o = valid ? idx % 20 : 0;
                float a = 0.f;
                if (valid) {
                    const f16* hp = sm.planeB + b * HP_STRIDE + kp * 32;
                    const float* wo = Wo + (size_t)o * 512 + kp * 32;
#pragma unroll
                    for (int k = 0; k < 32; k += 8) {
                        f16x8 hv = *(const f16x8*)(hp + k);
                        float4 wa = *(const float4*)(wo + k);
                        float4 wb = *(const float4*)(wo + k + 4);
                        a += (float)hv[0] * wa.x + (float)hv[1] * wa.y +
                             (float)hv[2] * wa.z + (float)hv[3] * wa.w +
                             (float)hv[4] * wb.x + (float)hv[5] * wb.y +
                             (float)hv[6] * wb.z + (float)hv[7] * wb.w;
                    }
                }
                a += __shfl_down(a, 8, 16);
                a += __shfl_down(a, 4, 16);
                a += __shfl_down(a, 2, 16);
                a += __shfl_down(a, 1, 16);
                if (valid && kp == 0)
                    out[((size_t)(gb8 + b) * 1024 + (t - 1)) * 20 + o] =
                        sigm_(a + bo[o]);
            }
        }

        // ===== epilogue: out(T-1) from h1(T-1) =============================
        if (tid < 64) wait_flags(flag1, T_STEPS, flag1, T_STEPS, lane);
        __syncthreads();
        stage_plane(H1g + ((T_STEPS - 1) & 1) * 4096, sm.planeB, tid);
        __syncthreads();
        {
            int p = tid >> 4, kp = tid & 15;
            int valid = (p < 10);
            int idx = r * 10 + p;
            int b = valid ? idx / 20 : 0, o = valid ? idx % 20 : 0;
            float a = 0.f;
            if (valid) {
                const f16* hp = sm.planeB + b * HP_STRIDE + kp * 32;
                const float* wo = Wo + (size_t)o * 512 + kp * 32;
#pragma unroll
                for (int k = 0; k < 32; k += 8) {
                    f16x8 hv = *(const f16x8*)(hp + k);
                    float4 wa = *(const float4*)(wo + k);
                    float4 wb = *(const float4*)(wo + k + 4);
                    a += (float)hv[0] * wa.x + (float)hv[1] * wa.y +
                         (float)hv[2] * wa.z + (float)hv[3] * wa.w +
                         (float)hv[4] * wb.x + (float)hv[5] * wb.y +
                         (float)hv[6] * wb.z + (float)hv[7] * wb.w;
                }
            }
            a += __shfl_down(a, 8, 16);
            a += __shfl_down(a, 4, 16);
            a += __shfl_down(a, 2, 16);
            a += __shfl_down(a, 1, 16);
            if (valid && kp == 0)
                out[((size_t)(gb8 + b) * 1024 + (T_STEPS - 1)) * 20 + o] =
                    sigm_(a + bo[o]);
        }
    }
}

extern "C" void kernel_launch(void* const* d_in, const int* in_sizes, int n_in,
                              void* d_out, int out_size, void* d_ws, size_t ws_size,
                              hipStream_t stream) {
    const float* x   = (const float*)d_in[0];
    const float* Wx0 = (const float*)d_in[1];
    const float* bx0 = (const float*)d_in[2];
    const float* Wh0 = (const float*)d_in[3];
    const float* Wx1 = (const float*)d_in[4];
    const float* bx1 = (const float*)d_in[5];
    const float* Wh1 = (const float*)d_in[6];
    const float* Wo  = (const float*)d_in[7];
    const float* bo  = (const float*)d_in[8];
    float* out = (float*)d_out;
    char*  ws  = (char*)d_ws;

    if (ws_size < (size_t)WS_NEED) return;   // fail visibly (out stays poisoned)

    zero_ws_kernel<<<128, 256, 0, stream>>>((unsigned*)ws, WS_NEED / 4);
    lstm_persist<<<256, 256, 0, stream>>>(x, Wx0, bx0, Wh0, Wx1, bx1, Wh1,
                                          Wo, bo, out, ws);
}